// Round 1
// baseline (1546.058 us; speedup 1.0000x reference)
//
#include <hip/hip_runtime.h>

namespace {

constexpr int NNODES = 50000;
constexpr int NEDGES = 800000;
constexpr int DIN  = 64;
constexpr int DHID = 128;
constexpr int DOUT = 64;

// ---------------------------------------------------------------------------
// Detect whether edge_index arrived as int64 (odd 32-bit words all zero,
// since values < 50000) or int32 (odd words are values, ~never zero).
// Writes flag: 1 => int64, 0 => int32.
__global__ __launch_bounds__(256) void detect_idx64(const unsigned int* __restrict__ raw,
                                                    int* __restrict__ flag) {
  __shared__ int s_any;
  if (threadIdx.x == 0) s_any = 0;
  __syncthreads();
  int any = 0;
  // Sample first 8192 words (32KB) -- safe for both layouts (min buffer 6.4MB)
  for (int i = 1 + 2 * (int)threadIdx.x; i < 8192; i += 512) {
    any |= (raw[i] != 0u) ? 1 : 0;
  }
  if (any) atomicOr(&s_any, 1);
  __syncthreads();
  if (threadIdx.x == 0) *flag = (s_any == 0) ? 1 : 0;
}

// Convert edge_index (either width) to int32 src/dst arrays; also compute
// in-degree counts (float) per dst.
__global__ __launch_bounds__(256) void convert_edges(const void* __restrict__ raw,
                                                     const int* __restrict__ flag,
                                                     int* __restrict__ src,
                                                     int* __restrict__ dst,
                                                     float* __restrict__ cnt) {
  const int is64 = *flag;  // uniform branch
  const int stride = gridDim.x * blockDim.x;
  for (int e = blockIdx.x * blockDim.x + threadIdx.x; e < NEDGES; e += stride) {
    int s, d;
    if (is64) {
      const long long* p = (const long long*)raw;
      s = (int)p[e];
      d = (int)p[NEDGES + e];
    } else {
      const int* p = (const int*)raw;
      s = p[e];
      d = p[NEDGES + e];
    }
    src[e] = s;
    dst[e] = d;
    atomicAdd(&cnt[d], 1.0f);
  }
}

// Scatter-add: for each edge, sum[dst] += xin[src] over D channels.
// One thread handles one edge x 4 channels (float4 gather, 4 atomics).
template <int D>
__global__ __launch_bounds__(256) void scatter_add(const float* __restrict__ xin,
                                                   const int* __restrict__ src,
                                                   const int* __restrict__ dst,
                                                   float* __restrict__ sum) {
  constexpr int C4 = D / 4;
  const int total = NEDGES * C4;
  const int stride = gridDim.x * blockDim.x;
  for (int t = blockIdx.x * blockDim.x + threadIdx.x; t < total; t += stride) {
    const int e = t / C4;
    const int c = t % C4;
    const int s = src[e];
    const int d = dst[e];
    const float4 v = reinterpret_cast<const float4*>(xin + (size_t)s * D)[c];
    float* o = sum + (size_t)d * D + (size_t)c * 4;
    atomicAdd(o + 0, v.x);
    atomicAdd(o + 1, v.y);
    atomicAdd(o + 2, v.z);
    atomicAdd(o + 3, v.w);
  }
}

// Fused SAGE layer: out[row, j] = act( (sumbuf[row]/max(cnt,1)) . Wl[:,j]
//                                      + bl[j] + xin[row] . Wr[:,j] )
// Column-tiled (JT cols per block, blockIdx.y = column block), weights in LDS.
template <int K, int J, int JT, bool RELU>
__global__ __launch_bounds__(256) void sage_layer(const float* __restrict__ sumbuf,
                                                  const float* __restrict__ cnt,
                                                  const float* __restrict__ xin,
                                                  const float* __restrict__ Wl,
                                                  const float* __restrict__ bl,
                                                  const float* __restrict__ Wr,
                                                  float* __restrict__ out) {
  constexpr int RPI = 256 / JT;  // rows per iteration
  __shared__ float sWl[K * JT];
  __shared__ float sWr[K * JT];
  __shared__ float sM[RPI * K];
  __shared__ float sX[RPI * K];
  const int cb = blockIdx.y;
  for (int i = threadIdx.x; i < K * JT; i += 256) {
    const int k = i / JT, jj = i % JT;
    sWl[i] = Wl[(size_t)k * J + cb * JT + jj];
    sWr[i] = Wr[(size_t)k * J + cb * JT + jj];
  }
  const int rl = threadIdx.x / JT;
  const int jj = threadIdx.x % JT;
  const float bias = bl[cb * JT + jj];
  for (int row0 = blockIdx.x * RPI; row0 < NNODES; row0 += gridDim.x * RPI) {
    for (int idx = threadIdx.x; idx < RPI * K; idx += 256) {
      const int r = idx / K, k = idx % K;
      const int row = row0 + r;
      if (row < NNODES) {
        const float inv = 1.0f / fmaxf(cnt[row], 1.0f);
        sM[idx] = sumbuf[(size_t)row * K + k] * inv;
        sX[idx] = xin[(size_t)row * K + k];
      }
    }
    __syncthreads();
    const int row = row0 + rl;
    if (row < NNODES) {
      float acc = bias;
#pragma unroll
      for (int k = 0; k < K; ++k) {
        acc += sM[rl * K + k] * sWl[k * JT + jj];
        acc += sX[rl * K + k] * sWr[k * JT + jj];
      }
      out[(size_t)row * J + cb * JT + jj] = RELU ? fmaxf(acc, 0.0f) : acc;
    }
    __syncthreads();
  }
}

// Dual projection for layer 2 (project BEFORE aggregation, halving atomics):
//   p[row,j] = hin[row] . Wl[:,j]          (to be aggregated over edges)
//   r[row,j] = hin[row] . Wr[:,j] + bl[j]  (self term, used in finalize)
template <int K, int J, int JT>
__global__ __launch_bounds__(256) void dual_project(const float* __restrict__ hin,
                                                    const float* __restrict__ Wl,
                                                    const float* __restrict__ Wr,
                                                    const float* __restrict__ bl,
                                                    float* __restrict__ pout,
                                                    float* __restrict__ rout) {
  constexpr int RPI = 256 / JT;
  __shared__ float sWl[K * JT];
  __shared__ float sWr[K * JT];
  __shared__ float sX[RPI * K];
  const int cb = blockIdx.y;
  for (int i = threadIdx.x; i < K * JT; i += 256) {
    const int k = i / JT, jj = i % JT;
    sWl[i] = Wl[(size_t)k * J + cb * JT + jj];
    sWr[i] = Wr[(size_t)k * J + cb * JT + jj];
  }
  const int rl = threadIdx.x / JT;
  const int jj = threadIdx.x % JT;
  const float bias = bl[cb * JT + jj];
  for (int row0 = blockIdx.x * RPI; row0 < NNODES; row0 += gridDim.x * RPI) {
    for (int idx = threadIdx.x; idx < RPI * K; idx += 256) {
      const int r = idx / K, k = idx % K;
      const int row = row0 + r;
      if (row < NNODES) sX[idx] = hin[(size_t)row * K + k];
    }
    __syncthreads();
    const int row = row0 + rl;
    if (row < NNODES) {
      float accp = 0.0f, accr = bias;
#pragma unroll
      for (int k = 0; k < K; ++k) {
        const float xv = sX[rl * K + k];
        accp += xv * sWl[k * JT + jj];
        accr += xv * sWr[k * JT + jj];
      }
      pout[(size_t)row * J + cb * JT + jj] = accp;
      rout[(size_t)row * J + cb * JT + jj] = accr;
    }
    __syncthreads();
  }
}

// out = sum2 / max(cnt,1) + r
__global__ __launch_bounds__(256) void finalize(const float* __restrict__ sum2,
                                                const float* __restrict__ cnt,
                                                const float* __restrict__ rbuf,
                                                float* __restrict__ out) {
  constexpr int C4 = DOUT / 4;
  const int total = NNODES * C4;
  const int stride = gridDim.x * blockDim.x;
  for (int t = blockIdx.x * blockDim.x + threadIdx.x; t < total; t += stride) {
    const int row = t / C4;
    const float inv = 1.0f / fmaxf(cnt[row], 1.0f);
    const float4 s = reinterpret_cast<const float4*>(sum2)[t];
    const float4 rr = reinterpret_cast<const float4*>(rbuf)[t];
    float4 o;
    o.x = fmaf(s.x, inv, rr.x);
    o.y = fmaf(s.y, inv, rr.y);
    o.z = fmaf(s.z, inv, rr.z);
    o.w = fmaf(s.w, inv, rr.w);
    reinterpret_cast<float4*>(out)[t] = o;
  }
}

}  // namespace

extern "C" void kernel_launch(void* const* d_in, const int* in_sizes, int n_in,
                              void* d_out, int out_size, void* d_ws, size_t ws_size,
                              hipStream_t stream) {
  const float* x   = (const float*)d_in[0];
  const void*  ei  = d_in[1];  // edge_index, int32 or int64 (detected at runtime)
  const float* Wl1 = (const float*)d_in[2];
  const float* bl1 = (const float*)d_in[3];
  const float* Wr1 = (const float*)d_in[4];
  const float* Wl2 = (const float*)d_in[5];
  const float* bl2 = (const float*)d_in[6];
  const float* Wr2 = (const float*)d_in[7];
  float* out = (float*)d_out;

  // Workspace layout (bytes, all float4-aligned):
  //   src   [E]  int32      @ 0          (3,200,000)
  //   dst   [E]  int32      @ 3,200,000  (3,200,000)
  //   flag  [1]  int32      @ 6,400,000  (256)
  //   cnt   [N]  f32        @ 6,400,256  (200,000)     --+
  //   sum1  [N,64] f32      @ 6,600,256  (12,800,000)    | zeroed by one memset
  //   sum2  [N,64] f32      @ 19,400,256 (12,800,000)  --+
  //   h     [N,128] f32     @ 32,200,256 (25,600,000)
  //   r     [N,64] f32      @ 57,800,256 (12,800,000)
  // total: 70,600,256 bytes.  sum1 is reused as p (= h @ W_l2) after layer 1.
  char* ws = (char*)d_ws;
  int*   src  = (int*)(ws + 0);
  int*   dst  = (int*)(ws + 3200000);
  int*   flag = (int*)(ws + 6400000);
  float* cnt  = (float*)(ws + 6400256);
  float* sum1 = (float*)(ws + 6600256);
  float* sum2 = (float*)(ws + 19400256);
  float* h    = (float*)(ws + 32200256);
  float* r    = (float*)(ws + 57800256);
  float* p    = sum1;  // safe: sum1's last read (sage_layer) precedes dual_project

  // Zero cnt + sum1 + sum2 (contiguous region)
  hipMemsetAsync(cnt, 0, 200000 + 12800000 + 12800000, stream);

  detect_idx64<<<1, 256, 0, stream>>>((const unsigned int*)ei, flag);
  convert_edges<<<1024, 256, 0, stream>>>(ei, flag, src, dst, cnt);

  // Layer 1: aggregate x (64ch) then project to 128
  scatter_add<DIN><<<4096, 256, 0, stream>>>(x, src, dst, sum1);
  sage_layer<DIN, DHID, 64, true><<<dim3(1024, 2), 256, 0, stream>>>(
      sum1, cnt, x, Wl1, bl1, Wr1, h);

  // Layer 2: project h to 64 first (mean commutes with linear), then aggregate
  dual_project<DHID, DOUT, 32><<<dim3(1024, 2), 256, 0, stream>>>(
      h, Wl2, Wr2, bl2, p, r);
  scatter_add<DOUT><<<4096, 256, 0, stream>>>(p, src, dst, sum2);
  finalize<<<2048, 256, 0, stream>>>(sum2, cnt, r, out);
}

// Round 2
// 449.058 us; speedup vs baseline: 3.4429x; 3.4429x over previous
//
#include <hip/hip_runtime.h>

namespace {

constexpr int NNODES = 50000;
constexpr int NEDGES = 800000;
constexpr int DIN  = 64;
constexpr int DHID = 128;
constexpr int DOUT = 64;

// ---------------------------------------------------------------------------
// Detect whether edge_index arrived as int64 (odd 32-bit words all zero,
// since values < 50000) or int32 (odd words are values, ~never zero).
// Writes flag: 1 => int64, 0 => int32.
__global__ __launch_bounds__(256) void detect_idx64(const unsigned int* __restrict__ raw,
                                                    int* __restrict__ flag) {
  __shared__ int s_any;
  if (threadIdx.x == 0) s_any = 0;
  __syncthreads();
  int any = 0;
  for (int i = 1 + 2 * (int)threadIdx.x; i < 8192; i += 512) {
    any |= (raw[i] != 0u) ? 1 : 0;
  }
  if (any) atomicOr(&s_any, 1);
  __syncthreads();
  if (threadIdx.x == 0) *flag = (s_any == 0) ? 1 : 0;
}

// Convert edge_index (either width) to int32 src/dst arrays + int degree histogram.
__global__ __launch_bounds__(256) void convert_edges(const void* __restrict__ raw,
                                                     const int* __restrict__ flag,
                                                     int* __restrict__ src,
                                                     int* __restrict__ dst,
                                                     int* __restrict__ deg) {
  const int is64 = *flag;  // uniform branch
  const int stride = gridDim.x * blockDim.x;
  for (int e = blockIdx.x * blockDim.x + threadIdx.x; e < NEDGES; e += stride) {
    int s, d;
    if (is64) {
      const long long* p = (const long long*)raw;
      s = (int)p[e];
      d = (int)p[NEDGES + e];
    } else {
      const int* p = (const int*)raw;
      s = p[e];
      d = p[NEDGES + e];
    }
    src[e] = s;
    dst[e] = d;
    atomicAdd(&deg[d], 1);
  }
}

// Single-block exclusive scan of deg[NNODES] -> row_ptr[NNODES+1], copy to cursor.
__global__ __launch_bounds__(1024) void scan_deg(const int* __restrict__ deg,
                                                 int* __restrict__ row_ptr,
                                                 int* __restrict__ cursor) {
  __shared__ int part[1024];
  const int t = threadIdx.x;
  constexpr int CH = (NNODES + 1023) / 1024;  // 49
  const int base = t * CH;
  int s = 0;
  for (int i = 0; i < CH; ++i) {
    const int idx = base + i;
    if (idx < NNODES) s += deg[idx];
  }
  part[t] = s;
  __syncthreads();
  // Hillis-Steele inclusive scan over 1024 partials
  for (int off = 1; off < 1024; off <<= 1) {
    const int v = part[t];
    const int add = (t >= off) ? part[t - off] : 0;
    __syncthreads();
    part[t] = v + add;
    __syncthreads();
  }
  if (t == 1023) row_ptr[NNODES] = part[1023];  // == NEDGES
  int prefix = (t == 0) ? 0 : part[t - 1];
  for (int i = 0; i < CH; ++i) {
    const int idx = base + i;
    if (idx < NNODES) {
      row_ptr[idx] = prefix;
      cursor[idx] = prefix;
      prefix += deg[idx];
    }
  }
}

// Fill CSR column list via per-node atomic cursors (int atomics, cheap).
__global__ __launch_bounds__(256) void fill_csr(const int* __restrict__ src,
                                                const int* __restrict__ dst,
                                                int* __restrict__ cursor,
                                                int* __restrict__ col) {
  const int stride = gridDim.x * blockDim.x;
  for (int e = blockIdx.x * blockDim.x + threadIdx.x; e < NEDGES; e += stride) {
    const int slot = atomicAdd(&cursor[dst[e]], 1);
    col[slot] = src[e];
  }
}

// Segment mean via gather: one wave (64 lanes == D channels) per node.
//   outbuf[v,c] = (1/max(deg,1)) * sum_{i in seg(v)} xin[col[i], c]  (+ radd[v,c] if FINAL)
template <int D, bool FINAL>
__global__ __launch_bounds__(256) void seg_mean(const float* __restrict__ xin,
                                                const int* __restrict__ row_ptr,
                                                const int* __restrict__ col,
                                                const float* __restrict__ radd,
                                                float* __restrict__ outbuf) {
  static_assert(D == 64, "one wave == one node's 64 channels");
  const int lane = threadIdx.x & 63;
  const int wid = (blockIdx.x * blockDim.x + threadIdx.x) >> 6;
  const int nw = (gridDim.x * blockDim.x) >> 6;
  for (int v = wid; v < NNODES; v += nw) {
    const int b = row_ptr[v];
    const int e = row_ptr[v + 1];
    float acc = 0.0f;
    int i = b;
    for (; i + 4 <= e; i += 4) {  // unroll x4: 4 independent gathers in flight
      const int s0 = col[i], s1 = col[i + 1], s2 = col[i + 2], s3 = col[i + 3];
      const float v0 = xin[(size_t)s0 * D + lane];
      const float v1 = xin[(size_t)s1 * D + lane];
      const float v2 = xin[(size_t)s2 * D + lane];
      const float v3 = xin[(size_t)s3 * D + lane];
      acc += (v0 + v1) + (v2 + v3);
    }
    for (; i < e; ++i) acc += xin[(size_t)col[i] * D + lane];
    const float inv = 1.0f / fmaxf((float)(e - b), 1.0f);
    float val = acc * inv;
    if (FINAL) val += radd[(size_t)v * D + lane];
    outbuf[(size_t)v * D + lane] = val;
  }
}

// Fused SAGE layer 1: out[row, j] = relu( mean[row] . Wl[:,j] + bl[j] + xin[row] . Wr[:,j] )
template <int K, int J, int JT, bool RELU>
__global__ __launch_bounds__(256) void sage_layer(const float* __restrict__ meanbuf,
                                                  const float* __restrict__ xin,
                                                  const float* __restrict__ Wl,
                                                  const float* __restrict__ bl,
                                                  const float* __restrict__ Wr,
                                                  float* __restrict__ out) {
  constexpr int RPI = 256 / JT;  // rows per iteration
  __shared__ float sWl[K * JT];
  __shared__ float sWr[K * JT];
  __shared__ float sM[RPI * K];
  __shared__ float sX[RPI * K];
  const int cb = blockIdx.y;
  for (int i = threadIdx.x; i < K * JT; i += 256) {
    const int k = i / JT, jj = i % JT;
    sWl[i] = Wl[(size_t)k * J + cb * JT + jj];
    sWr[i] = Wr[(size_t)k * J + cb * JT + jj];
  }
  const int rl = threadIdx.x / JT;
  const int jj = threadIdx.x % JT;
  const float bias = bl[cb * JT + jj];
  for (int row0 = blockIdx.x * RPI; row0 < NNODES; row0 += gridDim.x * RPI) {
    for (int idx = threadIdx.x; idx < RPI * K; idx += 256) {
      const int r = idx / K, k = idx % K;
      const int row = row0 + r;
      if (row < NNODES) {
        sM[idx] = meanbuf[(size_t)row * K + k];
        sX[idx] = xin[(size_t)row * K + k];
      }
    }
    __syncthreads();
    const int row = row0 + rl;
    if (row < NNODES) {
      float acc = bias;
#pragma unroll
      for (int k = 0; k < K; ++k) {
        acc += sM[rl * K + k] * sWl[k * JT + jj];
        acc += sX[rl * K + k] * sWr[k * JT + jj];
      }
      out[(size_t)row * J + cb * JT + jj] = RELU ? fmaxf(acc, 0.0f) : acc;
    }
    __syncthreads();
  }
}

// Dual projection for layer 2 (project BEFORE aggregation, halving gather width):
//   p[row,j] = hin[row] . Wl[:,j]
//   r[row,j] = hin[row] . Wr[:,j] + bl[j]
template <int K, int J, int JT>
__global__ __launch_bounds__(256) void dual_project(const float* __restrict__ hin,
                                                    const float* __restrict__ Wl,
                                                    const float* __restrict__ Wr,
                                                    const float* __restrict__ bl,
                                                    float* __restrict__ pout,
                                                    float* __restrict__ rout) {
  constexpr int RPI = 256 / JT;
  __shared__ float sWl[K * JT];
  __shared__ float sWr[K * JT];
  __shared__ float sX[RPI * K];
  const int cb = blockIdx.y;
  for (int i = threadIdx.x; i < K * JT; i += 256) {
    const int k = i / JT, jj = i % JT;
    sWl[i] = Wl[(size_t)k * J + cb * JT + jj];
    sWr[i] = Wr[(size_t)k * J + cb * JT + jj];
  }
  const int rl = threadIdx.x / JT;
  const int jj = threadIdx.x % JT;
  const float bias = bl[cb * JT + jj];
  for (int row0 = blockIdx.x * RPI; row0 < NNODES; row0 += gridDim.x * RPI) {
    for (int idx = threadIdx.x; idx < RPI * K; idx += 256) {
      const int r = idx / K, k = idx % K;
      const int row = row0 + r;
      if (row < NNODES) sX[idx] = hin[(size_t)row * K + k];
    }
    __syncthreads();
    const int row = row0 + rl;
    if (row < NNODES) {
      float accp = 0.0f, accr = bias;
#pragma unroll
      for (int k = 0; k < K; ++k) {
        const float xv = sX[rl * K + k];
        accp += xv * sWl[k * JT + jj];
        accr += xv * sWr[k * JT + jj];
      }
      pout[(size_t)row * J + cb * JT + jj] = accp;
      rout[(size_t)row * J + cb * JT + jj] = accr;
    }
    __syncthreads();
  }
}

}  // namespace

extern "C" void kernel_launch(void* const* d_in, const int* in_sizes, int n_in,
                              void* d_out, int out_size, void* d_ws, size_t ws_size,
                              hipStream_t stream) {
  const float* x   = (const float*)d_in[0];
  const void*  ei  = d_in[1];  // edge_index, int32 or int64 (detected at runtime)
  const float* Wl1 = (const float*)d_in[2];
  const float* bl1 = (const float*)d_in[3];
  const float* Wr1 = (const float*)d_in[4];
  const float* Wl2 = (const float*)d_in[5];
  const float* bl2 = (const float*)d_in[6];
  const float* Wr2 = (const float*)d_in[7];
  float* out = (float*)d_out;

  // Workspace layout (bytes):
  //   src     [E]    int32 @ 0           (3,200,000)
  //   dst     [E]    int32 @ 3,200,000   (3,200,000)
  //   col     [E]    int32 @ 6,400,000   (3,200,000)
  //   flag    [1]    int32 @ 9,600,000   (256)
  //   deg     [N]    int32 @ 9,600,256   (200,000)   <- only memset target
  //   row_ptr [N+1]  int32 @ 9,800,256   (200,064)
  //   cursor  [N]    int32 @ 10,000,320  (200,000)
  //   mean1   [N,64] f32   @ 10,200,320  (12,800,000)  -- reused as r
  //   h       [N,128]f32   @ 23,000,320  (25,600,000)
  //   p       [N,64] f32   @ 48,600,320  (12,800,000)
  // total: 61,400,320 bytes
  char* ws = (char*)d_ws;
  int*   src     = (int*)(ws + 0);
  int*   dst     = (int*)(ws + 3200000);
  int*   col     = (int*)(ws + 6400000);
  int*   flag    = (int*)(ws + 9600000);
  int*   deg     = (int*)(ws + 9600256);
  int*   row_ptr = (int*)(ws + 9800256);
  int*   cursor  = (int*)(ws + 10000320);
  float* mean1   = (float*)(ws + 10200320);
  float* h       = (float*)(ws + 23000320);
  float* p       = (float*)(ws + 48600320);
  float* r       = mean1;  // safe: mean1's last read (sage_layer) precedes dual_project's write

  hipMemsetAsync(deg, 0, 200000, stream);

  // CSR build
  detect_idx64<<<1, 256, 0, stream>>>((const unsigned int*)ei, flag);
  convert_edges<<<1024, 256, 0, stream>>>(ei, flag, src, dst, deg);
  scan_deg<<<1, 1024, 0, stream>>>(deg, row_ptr, cursor);
  fill_csr<<<1024, 256, 0, stream>>>(src, dst, cursor, col);

  // Layer 1: mean-aggregate x (gather, no atomics), then fused linear+relu
  seg_mean<DIN, false><<<12500, 256, 0, stream>>>(x, row_ptr, col, nullptr, mean1);
  sage_layer<DIN, DHID, 64, true><<<dim3(1024, 2), 256, 0, stream>>>(
      mean1, x, Wl1, bl1, Wr1, h);

  // Layer 2: project first (mean commutes with linear), then gather + fused add
  dual_project<DHID, DOUT, 32><<<dim3(1024, 2), 256, 0, stream>>>(
      h, Wl2, Wr2, bl2, p, r);
  seg_mean<DOUT, true><<<12500, 256, 0, stream>>>(p, row_ptr, col, r, out);
}

// Round 3
// 332.657 us; speedup vs baseline: 4.6476x; 1.3499x over previous
//
#include <hip/hip_runtime.h>

namespace {

constexpr int NNODES = 50000;
constexpr int NEDGES = 800000;
constexpr int DIN  = 64;
constexpr int DHID = 128;
constexpr int DOUT = 64;
constexpr int NBLK = (NNODES + 255) / 256;  // 196 scan blocks

// ---------------------------------------------------------------------------
// Detect whether edge_index arrived as int64 (odd 32-bit words all zero,
// since values < 50000) or int32 (odd words are values, ~never zero).
// Writes flag: 1 => int64, 0 => int32.
__global__ __launch_bounds__(256) void detect_idx64(const unsigned int* __restrict__ raw,
                                                    int* __restrict__ flag) {
  __shared__ int s_any;
  if (threadIdx.x == 0) s_any = 0;
  __syncthreads();
  int any = 0;
  for (int i = 1 + 2 * (int)threadIdx.x; i < 8192; i += 512) {
    any |= (raw[i] != 0u) ? 1 : 0;
  }
  if (any) atomicOr(&s_any, 1);
  __syncthreads();
  if (threadIdx.x == 0) *flag = (s_any == 0) ? 1 : 0;
}

// Degree histogram straight from raw edge_index (either width).
__global__ __launch_bounds__(256) void deg_hist(const void* __restrict__ raw,
                                                const int* __restrict__ flag,
                                                int* __restrict__ deg) {
  const int is64 = *flag;  // uniform branch
  const int stride = gridDim.x * blockDim.x;
  for (int e = blockIdx.x * blockDim.x + threadIdx.x; e < NEDGES; e += stride) {
    int d;
    if (is64) {
      d = (int)((const long long*)raw)[NEDGES + e];
    } else {
      d = ((const int*)raw)[NEDGES + e];
    }
    atomicAdd(&deg[d], 1);
  }
}

// --- Hierarchical exclusive scan of deg[NNODES] ----------------------------
// Phase 1: per-block (256 elems) sums -> bsum[NBLK]
__global__ __launch_bounds__(256) void scan_phase1(const int* __restrict__ deg,
                                                   int* __restrict__ bsum) {
  const int idx = blockIdx.x * 256 + threadIdx.x;
  int v = (idx < NNODES) ? deg[idx] : 0;
  const int lane = threadIdx.x & 63;
  const int w = threadIdx.x >> 6;
#pragma unroll
  for (int off = 32; off; off >>= 1) v += __shfl_down(v, off, 64);
  __shared__ int wsum[4];
  if (lane == 0) wsum[w] = v;
  __syncthreads();
  if (threadIdx.x == 0) bsum[blockIdx.x] = wsum[0] + wsum[1] + wsum[2] + wsum[3];
}

// Phase 2: single block scans NBLK partials in-place (-> exclusive offsets),
// writes row_ptr[NNODES] = total (== NEDGES).
__global__ __launch_bounds__(256) void scan_phase2(int* __restrict__ bsum,
                                                   int* __restrict__ row_ptr) {
  __shared__ int sh[256];
  const int t = threadIdx.x;
  const int v = (t < NBLK) ? bsum[t] : 0;
  sh[t] = v;
  __syncthreads();
#pragma unroll
  for (int off = 1; off < 256; off <<= 1) {
    const int val = sh[t];
    const int add = (t >= off) ? sh[t - off] : 0;
    __syncthreads();
    sh[t] = val + add;
    __syncthreads();
  }
  if (t < NBLK) bsum[t] = sh[t] - v;  // exclusive
  if (t == 255) row_ptr[NNODES] = sh[255];
}

// Phase 3: block-level exclusive scan + block offset -> row_ptr, cursor.
__global__ __launch_bounds__(256) void scan_phase3(const int* __restrict__ deg,
                                                   const int* __restrict__ bsum,
                                                   int* __restrict__ row_ptr,
                                                   int* __restrict__ cursor) {
  const int idx = blockIdx.x * 256 + threadIdx.x;
  const int v = (idx < NNODES) ? deg[idx] : 0;
  const int lane = threadIdx.x & 63;
  const int w = threadIdx.x >> 6;
  int s = v;  // inclusive scan within wave
#pragma unroll
  for (int off = 1; off < 64; off <<= 1) {
    const int t = __shfl_up(s, off, 64);
    if (lane >= off) s += t;
  }
  __shared__ int wsum[4];
  if (lane == 63) wsum[w] = s;
  __syncthreads();
  int wo = 0;
  for (int i = 0; i < 4; ++i) wo += (i < w) ? wsum[i] : 0;
  const int excl = bsum[blockIdx.x] + wo + (s - v);
  if (idx < NNODES) {
    row_ptr[idx] = excl;
    cursor[idx] = excl;
  }
}

// Fill CSR column list straight from raw edge_index via atomic cursors.
__global__ __launch_bounds__(256) void fill_csr(const void* __restrict__ raw,
                                                const int* __restrict__ flag,
                                                int* __restrict__ cursor,
                                                int* __restrict__ col) {
  const int is64 = *flag;
  const int stride = gridDim.x * blockDim.x;
  for (int e = blockIdx.x * blockDim.x + threadIdx.x; e < NEDGES; e += stride) {
    int s, d;
    if (is64) {
      const long long* p = (const long long*)raw;
      s = (int)p[e];
      d = (int)p[NEDGES + e];
    } else {
      const int* p = (const int*)raw;
      s = p[e];
      d = p[NEDGES + e];
    }
    const int slot = atomicAdd(&cursor[d], 1);
    col[slot] = s;
  }
}

// Segment mean via gather: one wave (64 lanes == D channels) per node.
//   outbuf[v,c] = (1/max(deg,1)) * sum_{i in seg(v)} xin[col[i], c]  (+ radd[v,c] if FINAL)
template <int D, bool FINAL>
__global__ __launch_bounds__(256) void seg_mean(const float* __restrict__ xin,
                                                const int* __restrict__ row_ptr,
                                                const int* __restrict__ col,
                                                const float* __restrict__ radd,
                                                float* __restrict__ outbuf) {
  static_assert(D == 64, "one wave == one node's 64 channels");
  const int lane = threadIdx.x & 63;
  const int wid = (blockIdx.x * blockDim.x + threadIdx.x) >> 6;
  const int nw = (gridDim.x * blockDim.x) >> 6;
  for (int v = wid; v < NNODES; v += nw) {
    const int b = row_ptr[v];
    const int e = row_ptr[v + 1];
    float acc = 0.0f;
    int i = b;
    for (; i + 4 <= e; i += 4) {  // unroll x4: 4 independent gathers in flight
      const int s0 = col[i], s1 = col[i + 1], s2 = col[i + 2], s3 = col[i + 3];
      const float v0 = xin[(size_t)s0 * D + lane];
      const float v1 = xin[(size_t)s1 * D + lane];
      const float v2 = xin[(size_t)s2 * D + lane];
      const float v3 = xin[(size_t)s3 * D + lane];
      acc += (v0 + v1) + (v2 + v3);
    }
    for (; i < e; ++i) acc += xin[(size_t)col[i] * D + lane];
    const float inv = 1.0f / fmaxf((float)(e - b), 1.0f);
    float val = acc * inv;
    if (FINAL) val += radd[(size_t)v * D + lane];
    outbuf[(size_t)v * D + lane] = val;
  }
}

// Fused SAGE layer 1: out[row, j] = relu( mean[row] . Wl[:,j] + bl[j] + xin[row] . Wr[:,j] )
template <int K, int J, int JT, bool RELU>
__global__ __launch_bounds__(256) void sage_layer(const float* __restrict__ meanbuf,
                                                  const float* __restrict__ xin,
                                                  const float* __restrict__ Wl,
                                                  const float* __restrict__ bl,
                                                  const float* __restrict__ Wr,
                                                  float* __restrict__ out) {
  constexpr int RPI = 256 / JT;  // rows per iteration
  __shared__ float sWl[K * JT];
  __shared__ float sWr[K * JT];
  __shared__ float sM[RPI * K];
  __shared__ float sX[RPI * K];
  const int cb = blockIdx.y;
  for (int i = threadIdx.x; i < K * JT; i += 256) {
    const int k = i / JT, jj = i % JT;
    sWl[i] = Wl[(size_t)k * J + cb * JT + jj];
    sWr[i] = Wr[(size_t)k * J + cb * JT + jj];
  }
  const int rl = threadIdx.x / JT;
  const int jj = threadIdx.x % JT;
  const float bias = bl[cb * JT + jj];
  for (int row0 = blockIdx.x * RPI; row0 < NNODES; row0 += gridDim.x * RPI) {
    for (int idx = threadIdx.x; idx < RPI * K; idx += 256) {
      const int r = idx / K, k = idx % K;
      const int row = row0 + r;
      if (row < NNODES) {
        sM[idx] = meanbuf[(size_t)row * K + k];
        sX[idx] = xin[(size_t)row * K + k];
      }
    }
    __syncthreads();
    const int row = row0 + rl;
    if (row < NNODES) {
      float acc = bias;
#pragma unroll
      for (int k = 0; k < K; ++k) {
        acc += sM[rl * K + k] * sWl[k * JT + jj];
        acc += sX[rl * K + k] * sWr[k * JT + jj];
      }
      out[(size_t)row * J + cb * JT + jj] = RELU ? fmaxf(acc, 0.0f) : acc;
    }
    __syncthreads();
  }
}

// Dual projection for layer 2 (project BEFORE aggregation, halving gather width):
//   p[row,j] = hin[row] . Wl[:,j]
//   r[row,j] = hin[row] . Wr[:,j] + bl[j]
template <int K, int J, int JT>
__global__ __launch_bounds__(256) void dual_project(const float* __restrict__ hin,
                                                    const float* __restrict__ Wl,
                                                    const float* __restrict__ Wr,
                                                    const float* __restrict__ bl,
                                                    float* __restrict__ pout,
                                                    float* __restrict__ rout) {
  constexpr int RPI = 256 / JT;
  __shared__ float sWl[K * JT];
  __shared__ float sWr[K * JT];
  __shared__ float sX[RPI * K];
  const int cb = blockIdx.y;
  for (int i = threadIdx.x; i < K * JT; i += 256) {
    const int k = i / JT, jj = i % JT;
    sWl[i] = Wl[(size_t)k * J + cb * JT + jj];
    sWr[i] = Wr[(size_t)k * J + cb * JT + jj];
  }
  const int rl = threadIdx.x / JT;
  const int jj = threadIdx.x % JT;
  const float bias = bl[cb * JT + jj];
  for (int row0 = blockIdx.x * RPI; row0 < NNODES; row0 += gridDim.x * RPI) {
    for (int idx = threadIdx.x; idx < RPI * K; idx += 256) {
      const int r = idx / K, k = idx % K;
      const int row = row0 + r;
      if (row < NNODES) sX[idx] = hin[(size_t)row * K + k];
    }
    __syncthreads();
    const int row = row0 + rl;
    if (row < NNODES) {
      float accp = 0.0f, accr = bias;
#pragma unroll
      for (int k = 0; k < K; ++k) {
        const float xv = sX[rl * K + k];
        accp += xv * sWl[k * JT + jj];
        accr += xv * sWr[k * JT + jj];
      }
      pout[(size_t)row * J + cb * JT + jj] = accp;
      rout[(size_t)row * J + cb * JT + jj] = accr;
    }
    __syncthreads();
  }
}

}  // namespace

extern "C" void kernel_launch(void* const* d_in, const int* in_sizes, int n_in,
                              void* d_out, int out_size, void* d_ws, size_t ws_size,
                              hipStream_t stream) {
  const float* x   = (const float*)d_in[0];
  const void*  ei  = d_in[1];  // edge_index, int32 or int64 (detected at runtime)
  const float* Wl1 = (const float*)d_in[2];
  const float* bl1 = (const float*)d_in[3];
  const float* Wr1 = (const float*)d_in[4];
  const float* Wl2 = (const float*)d_in[5];
  const float* bl2 = (const float*)d_in[6];
  const float* Wr2 = (const float*)d_in[7];
  float* out = (float*)d_out;

  // Workspace layout (bytes):
  //   col     [E]    int32 @ 0          (3,200,000)
  //   flag    [1]    int32 @ 3,200,000  (256)
  //   deg     [N]    int32 @ 3,200,256  (200,000)   <- only memset target
  //   row_ptr [N+1]  int32 @ 3,400,256  (200,064)
  //   cursor  [N]    int32 @ 3,600,320  (200,000)
  //   bsum    [NBLK] int32 @ 3,800,320  (1,024 padded)
  //   mean1   [N,64] f32   @ 3,801,344  (12,800,000)  -- reused as r
  //   h       [N,128]f32   @ 16,601,344 (25,600,000)
  //   p       [N,64] f32   @ 42,201,344 (12,800,000)
  // total: 55,001,344 bytes
  char* ws = (char*)d_ws;
  int*   col     = (int*)(ws + 0);
  int*   flag    = (int*)(ws + 3200000);
  int*   deg     = (int*)(ws + 3200256);
  int*   row_ptr = (int*)(ws + 3400256);
  int*   cursor  = (int*)(ws + 3600320);
  int*   bsum    = (int*)(ws + 3800320);
  float* mean1   = (float*)(ws + 3801344);
  float* h       = (float*)(ws + 16601344);
  float* p       = (float*)(ws + 42201344);
  float* r       = mean1;  // safe: mean1's last read (sage_layer) precedes dual_project's write

  hipMemsetAsync(deg, 0, 200000, stream);

  // CSR build
  detect_idx64<<<1, 256, 0, stream>>>((const unsigned int*)ei, flag);
  deg_hist<<<1024, 256, 0, stream>>>(ei, flag, deg);
  scan_phase1<<<NBLK, 256, 0, stream>>>(deg, bsum);
  scan_phase2<<<1, 256, 0, stream>>>(bsum, row_ptr);
  scan_phase3<<<NBLK, 256, 0, stream>>>(deg, bsum, row_ptr, cursor);
  fill_csr<<<1024, 256, 0, stream>>>(ei, flag, cursor, col);

  // Layer 1: mean-aggregate x (gather, no atomics), then fused linear+relu
  seg_mean<DIN, false><<<12500, 256, 0, stream>>>(x, row_ptr, col, nullptr, mean1);
  sage_layer<DIN, DHID, 64, true><<<dim3(1024, 2), 256, 0, stream>>>(
      mean1, x, Wl1, bl1, Wr1, h);

  // Layer 2: project first (mean commutes with linear), then gather + fused add
  dual_project<DHID, DOUT, 32><<<dim3(1024, 2), 256, 0, stream>>>(
      h, Wl2, Wr2, bl2, p, r);
  seg_mean<DOUT, true><<<12500, 256, 0, stream>>>(p, row_ptr, col, r, out);
}